// Round 4
// baseline (652.419 us; speedup 1.0000x reference)
//
#include <hip/hip_runtime.h>

// 5x5 morphological dilation with all-ones SE == 5x5 sliding max filter.
// fp32, NCHW (8,3,2048,2048). Memory-bound: target ~1x read + 1x write.

static constexpr float NEG = -10000.0f;   // reference pads with -MAX_VAL
static constexpr int W = 2048, H = 2048;
static constexpr int TILE_W = 256;        // px per wave in x (64 lanes * float4)
static constexpr int ROWS = 64;           // output rows per wave (rolling)

__device__ __forceinline__ float4 f4max(float4 a, float4 b) {
  return make_float4(fmaxf(a.x, b.x), fmaxf(a.y, b.y),
                     fmaxf(a.z, b.z), fmaxf(a.w, b.w));
}
__device__ __forceinline__ float4 f4splat(float v) { return make_float4(v, v, v, v); }

__global__ __launch_bounds__(256, 4)
void dilate5x5(const float* __restrict__ in, float* __restrict__ out) {
  const int lane  = threadIdx.x & 63;
  const int wv    = threadIdx.x >> 6;          // wave within block (0..3)
  const int tx    = blockIdx.x;                // x-tile (0..7)
  const int strip = blockIdx.y * 4 + wv;       // y-strip (0..31)
  const int img   = blockIdx.z;                // B*C plane (0..23)

  const float* __restrict__ src = in  + (size_t)img * W * H;
  float* __restrict__       dst = out + (size_t)img * W * H;

  const int x0 = tx * TILE_W + lane * 4;       // this lane's float4 px
  const int y0 = strip * ROWS;

  // halo float4: lane 0 covers [x_tile-4 .. x_tile-1], lane 63 covers [x_tile+256 .. +259]
  const int  hx        = (lane == 0) ? (tx * TILE_W - 4) : (tx * TILE_W + TILE_W);
  const bool haloLane  = (lane == 0) || (lane == 63);
  const bool haloValid = haloLane && (hx >= 0) && (hx < W);

  auto ldm = [&](int y) -> float4 {
    return (y >= 0 && y < H)
      ? *reinterpret_cast<const float4*>(src + (size_t)y * W + x0)
      : f4splat(NEG);
  };
  auto ldh = [&](int y) -> float4 {
    return (haloValid && y >= 0 && y < H)
      ? *reinterpret_cast<const float4*>(src + (size_t)y * W + hx)
      : f4splat(NEG);
  };

  // ---- prime vertical rolling state for y = y0 ----
  // vm5(y) = max( q(y-2), q(y), r(y+2) ),  q(y) = max(r(y), r(y+1))
  float4 rm2 = ldm(y0 - 2), rm1 = ldm(y0 - 1);
  float4 c0  = ldm(y0),     c1  = ldm(y0 + 1);
  float4 qA  = f4max(rm2, rm1);   // q(y0-2)
  float4 qB  = f4max(rm1, c0);    // q(y0-1)

  float4 hm2 = ldh(y0 - 2), hm1 = ldh(y0 - 1);
  float4 h0  = ldh(y0),     h1  = ldh(y0 + 1);
  float4 hqA = f4max(hm2, hm1);
  float4 hqB = f4max(hm1, h0);

  #pragma unroll 2   // shift chains have period 2 -> copies cancel under SSA
  for (int i = 0; i < ROWS; ++i) {
    const int y = y0 + i;
    float4 nc  = ldm(y + 2);
    float4 hnc = ldh(y + 2);

    float4 qy = f4max(c0, c1);               // q(y)
    float4 vm = f4max(f4max(qA, qy), nc);    // vertical 5-max at row y

    float4 hqy = f4max(h0, h1);
    float4 hvm = f4max(f4max(hqA, hqy), hnc);

    // horizontal neighbors: a = [pz,pw, vm.x,vm.y,vm.z,vm.w, nx,ny] = px x0-2 .. x0+5
    float pz = __shfl_up(vm.z, 1);
    float pw = __shfl_up(vm.w, 1);
    float nx = __shfl_down(vm.x, 1);
    float ny = __shfl_down(vm.y, 1);
    if (lane == 0)  { pz = hvm.z; pw = hvm.w; }   // tile-left halo (or -MAX at image edge)
    if (lane == 63) { nx = hvm.x; ny = hvm.y; }   // tile-right halo

    const float m12 = fmaxf(pw,   vm.x);
    const float m23 = fmaxf(vm.x, vm.y);
    const float m34 = fmaxf(vm.y, vm.z);
    const float m45 = fmaxf(vm.z, vm.w);
    const float m56 = fmaxf(vm.w, nx);
    float4 o;
    o.x = fmaxf(fmaxf(pz,  m12), m34);   // max(a0..a4)
    o.y = fmaxf(fmaxf(m12, m34), vm.w);  // max(a1..a5)
    o.z = fmaxf(fmaxf(m23, m45), nx);    // max(a2..a6)
    o.w = fmaxf(fmaxf(m34, m56), ny);    // max(a3..a7)

    *reinterpret_cast<float4*>(dst + (size_t)y * W + x0) = o;

    // rolling shift (period-2 chains; unroll 2 removes the movs)
    qA = qB;  qB = qy;  c0 = c1;  c1 = nc;
    hqA = hqB; hqB = hqy; h0 = h1; h1 = hnc;
  }
}

extern "C" void kernel_launch(void* const* d_in, const int* in_sizes, int n_in,
                              void* d_out, int out_size, void* d_ws, size_t ws_size,
                              hipStream_t stream) {
  const float* img = (const float*)d_in[0];
  float*       out = (float*)d_out;
  const int nimg = in_sizes[0] / (W * H);         // B*C = 24
  dim3 grid(W / TILE_W, H / (ROWS * 4), nimg);    // (8, 8, 24)
  dilate5x5<<<grid, 256, 0, stream>>>(img, out);
}